// Round 4
// baseline (449.899 us; speedup 1.0000x reference)
//
#include <hip/hip_runtime.h>
#include <hip/hip_fp16.h>

// reaction_diffusion, 4-kernel pipeline (R15: pass-A elimination — per-node
// counts + colsum computed in partition via fire-and-forget global atomics):
//   1. transpose: x[64,N] -> xth[N,64] fp16; zeroes colsum/cnt_node/gcur.
//   2. partition: dual-side bucket multisplit (512 thr, 76KB LDS). Per edge
//      also issues 4 non-returning global atomics: cnt_node[i]++,
//      cnt_node[N+j]++, colsum[i]+=wd, colsum[N+j]+=wr. These pipeline through
//      L2 and do not stall the wave.
//   3. sortgather: one 512-thr block per (side,bucket). Stage runs into 9 int2
//      regs (read once). NO pass A: cnt[] comes from cnt_node via one
//      coalesced 128-int load (R14 post-mortem: per-payload LDS atomics are
//      the dominant cost — gather was proven latency-free by the L2-residency
//      experiment: FETCH 95.7->25.1 MB with zero time delta). Scan (oct-pad),
//      zero pads, pass B (1 rtn LDS atomic + 1 ds_write per payload), then
//      oct-split uint4 gather: 8 lane-groups of 8, one payload per group per
//      oct, each lane loads uint4 (16 B = 8 batches) -> 1 VMEM per 8 payloads;
//      3-level shfl_xor combine; lanes 0-7 store uint4.
//   4. final: out[b,v] = tanh(colr*x - msgr + br) + (cold*x - msgd + bd) + x
// side 0 (dest = ei): w_main=wr -> msgr, w_col=wd -> cold
// side 1 (dest = ej): w_main=wd -> msgd, w_col=wr -> colr
// stage-1 payload int2: x=(bkt:9<<23)|(dl:7<<16)|(other:16), y=bf16(wm)<<16|bf16(wc)
// sorted payload int: (bf16(wm)<<16)|other:16   -- requires N <= 65536
// colsum is f32-exact now (partition atomics use raw float weights).

#define BKT_SHIFT 7
#define BKT_NODES 128
#define RCAP 4608     // per-(side,bucket) run capacity: mean 4096, +8 sigma
#define RCAP2 5504    // oct-padded bound (4608 + 128*7)
#define CH 4096       // partition chunk size (= 8 * 512 threads)
#define NBP 512       // padded per-side bin count (N <= 65536)

__device__ __forceinline__ unsigned bf16_rne(float f) {
    unsigned u = __float_as_uint(f);
    unsigned rb = (u >> 16) & 1u;
    u += 0x7FFFu + rb;
    return u >> 16;
}
__device__ __forceinline__ float bf16_hi(int y) {
    return __uint_as_float((unsigned)y & 0xFFFF0000u);
}

// kernel 1: x [64,N] -> xth [N,64] fp16; zeroes zbuf (colsum|cnt_node|gcur).
__global__ void transpose_kernel(const float* __restrict__ x, __half* __restrict__ xth,
                                 int* __restrict__ zbuf, int nz, int N) {
    __shared__ float tile[64][65];
    int v0 = blockIdx.x * 64;
    int tx = threadIdx.x;   // 0..63
    int ty = threadIdx.y;   // 0..15
    int flat = blockIdx.x * 1024 + ty * 64 + tx;
    if (flat < nz) zbuf[flat] = 0;
    if (v0 + tx < N) {
        for (int b = ty; b < 64; b += 16)
            tile[tx][b] = x[b * N + v0 + tx];
    }
    __syncthreads();
    for (int vl = ty; vl < 64; vl += 16) {
        int v = v0 + vl;
        if (v < N)
            xth[(size_t)v * 64 + tx] = __float2half(tile[vl][tx]);
    }
}

// kernel 2: dual-side chunked multi-split; edges in registers (read once).
// Also accumulates per-node payload counts + colsum via non-rtn global atomics.
__global__ void __launch_bounds__(512) partition_kernel(
        const int* __restrict__ ei, const int* __restrict__ ej,
        const float* __restrict__ wr, const float* __restrict__ wd,
        int* __restrict__ gcur, int2* __restrict__ runs,
        int* __restrict__ cnt_node, float* __restrict__ colsum,
        int E, int NB, int N) {
    __shared__ int cnt[2 * NBP];     // 4 KB
    __shared__ int base_a[2 * NBP];  // 4 KB
    __shared__ int gb[2 * NBP];      // 4 KB
    __shared__ int2 buf[2 * CH];     // 64 KB

    int tid = threadIdx.x;
    int e0 = blockIdx.x * CH;
    int ch_len = min(CH, E - e0);
    if (ch_len <= 0) return;

    int my_i[8], my_j[8];
    unsigned my_w[8];
    #pragma unroll
    for (int k = 0; k < 8; ++k) {
        int t = tid + k * 512;
        if (t < ch_len) {
            int e = e0 + t;
            int iv = ei[e], jv = ej[e];
            float wrv = wr[e], wdv = wd[e];
            my_i[k] = iv;
            my_j[k] = jv;
            my_w[k] = (bf16_rne(wrv) << 16) | bf16_rne(wdv);
            // dest-node histograms + column sums (fire-and-forget)
            atomicAdd(&cnt_node[iv], 1);
            atomicAdd(&cnt_node[N + jv], 1);
            atomicAdd(&colsum[iv], wdv);        // side 0: cold = sum wd (ei=v)
            atomicAdd(&colsum[N + jv], wrv);    // side 1: colr = sum wr (ej=v)
        } else {
            my_i[k] = -1;
        }
    }

    for (int b = tid; b < 2 * NBP; b += 512) cnt[b] = 0;
    __syncthreads();
    #pragma unroll
    for (int k = 0; k < 8; ++k) {
        if (my_i[k] >= 0) {
            atomicAdd(&cnt[my_i[k] >> BKT_SHIFT], 1);
            atomicAdd(&cnt[NBP + (my_j[k] >> BKT_SHIFT)], 1);
        }
    }
    __syncthreads();
    if (tid < 64) {
        int carry = 0;
        #pragma unroll
        for (int c = 0; c < (2 * NBP) / 64; ++c) {
            int idx = c * 64 + tid;
            int val = cnt[idx];
            int scan = val;
            for (int off = 1; off < 64; off <<= 1) {
                int n = __shfl_up(scan, off, 64);
                if (tid >= off) scan += n;
            }
            int excl = scan - val + carry;
            base_a[idx] = excl;
            cnt[idx] = excl;            // becomes cursor
            carry += __shfl(scan, 63, 64);
        }
    }
    __syncthreads();
    #pragma unroll
    for (int k = 0; k < 8; ++k) {
        if (my_i[k] >= 0) {
            int i = my_i[k], j = my_j[k];
            unsigned wv = my_w[k];
            int b0 = i >> BKT_SHIFT;
            int p0 = atomicAdd(&cnt[b0], 1);
            buf[p0] = make_int2((int)(((unsigned)b0 << 23) | ((unsigned)(i & 127) << 16) | (unsigned)j),
                                (int)wv);
            int b1 = j >> BKT_SHIFT;
            int p1 = atomicAdd(&cnt[NBP + b1], 1);
            buf[p1] = make_int2((int)(((unsigned)b1 << 23) | ((unsigned)(j & 127) << 16) | (unsigned)i),
                                (int)((wv << 16) | (wv >> 16)));
        }
    }
    __syncthreads();
    for (int cb = tid; cb < 2 * NBP; cb += 512) {
        int n = cnt[cb] - base_a[cb];
        if (n > 0) {
            int side = cb >> 9;
            int bkt = cb & (NBP - 1);
            gb[cb] = atomicAdd(&gcur[side * NB + bkt], n);
        }
    }
    __syncthreads();
    int total = 2 * ch_len;
    for (int t = tid; t < total; t += 512) {
        int2 p = buf[t];
        int side = (t >= ch_len) ? 1 : 0;
        int bkt = ((unsigned)p.x >> 23) & 0x1FF;
        int cb = side * NBP + bkt;
        int rank = gb[cb] + (t - base_a[cb]);
        if (rank < RCAP)
            runs[((size_t)(side * NB + bkt)) * RCAP + rank] = p;
    }
}

// accumulate one payload (weight in hi16 of P, 8 batches from uint4 D)
#define ACC8(P, D)                                                        \
    {                                                                     \
        float wv_ = bf16_hi(P);                                           \
        float2 f_;                                                        \
        f_ = __half22float2(*(const __half2*)&(D).x);                     \
        a0 = fmaf(wv_, f_.x, a0); a1 = fmaf(wv_, f_.y, a1);               \
        f_ = __half22float2(*(const __half2*)&(D).y);                     \
        a2 = fmaf(wv_, f_.x, a2); a3 = fmaf(wv_, f_.y, a3);               \
        f_ = __half22float2(*(const __half2*)&(D).z);                     \
        a4 = fmaf(wv_, f_.x, a4); a5 = fmaf(wv_, f_.y, a5);               \
        f_ = __half22float2(*(const __half2*)&(D).w);                     \
        a6 = fmaf(wv_, f_.x, a6); a7 = fmaf(wv_, f_.y, a7);               \
    }

#define COMB3(A) { A += __shfl_xor(A, 8); A += __shfl_xor(A, 16); A += __shfl_xor(A, 32); }

// kernel 3: per (side,bucket): runs staged once into regs; cnt from global
// (NO per-payload pass A); scan; pass B (1 rtn LDS atomic + 1 ds_write per
// payload); oct-split uint4 gather. ~22 KB LDS, 512 thr.
__global__ void __launch_bounds__(512) sortgather_kernel(
        const int* __restrict__ gcur, const int2* __restrict__ runs,
        const int* __restrict__ cnt_node,
        const __half* __restrict__ xth, __half* __restrict__ msg,
        int NB, int N) {
    __shared__ int cnt[BKT_NODES];
    __shared__ int cur[BKT_NODES];
    __shared__ int pb[BKT_NODES];
    __shared__ int dst[RCAP2];                  // 21.5 KB

    int sb = blockIdx.x;               // side*NB + b
    int side = (sb >= NB) ? 1 : 0;
    int b = sb - side * NB;
    int v0 = b << BKT_SHIFT;
    int len = min(gcur[sb], RCAP);
    size_t roff = (size_t)sb * RCAP;
    int tid = threadIdx.x;

    // register-stage the whole run: 9 * 512 = 4608 = RCAP. Single global read.
    // valid payloads never have x == -1 (bkt field <= 390 < 511).
    int2 my[9];
    #pragma unroll
    for (int k = 0; k < 9; ++k) {
        int t = tid + k * 512;
        if (t < len) my[k] = runs[roff + t];
        else my[k].x = -1;
    }

    // per-node counts from partition's global histogram (one coalesced load)
    if (tid < BKT_NODES) {
        int v = v0 + tid;
        cnt[tid] = (v < N) ? cnt_node[side * N + v] : 0;
    }
    __syncthreads();
    if (tid < 64) {
        int carry = 0;
        #pragma unroll
        for (int c = 0; c < BKT_NODES / 64; ++c) {
            int idx = c * 64 + tid;
            int val = (cnt[idx] + 7) & ~7;       // oct-padded
            int scan = val;
            for (int off = 1; off < 64; off <<= 1) {
                int n = __shfl_up(scan, off, 64);
                if (tid >= off) scan += n;
            }
            int excl = scan - val + carry;
            pb[idx] = excl;
            cur[idx] = excl;
            carry += __shfl(scan, 63, 64);
        }
    }
    __syncthreads();
    if (tid < BKT_NODES) {
        int pc = (cnt[tid] + 7) & ~7;
        for (int t = cnt[tid]; t < pc; ++t) dst[pb[tid] + t] = 0;   // zero pads
    }
    __syncthreads();
    // pass B: place compact payloads sorted by dest node, from registers
    #pragma unroll
    for (int k = 0; k < 9; ++k) {
        if (my[k].x != -1) {
            int dl = ((unsigned)my[k].x >> 16) & 0x7F;
            int pos = atomicAdd(&cur[dl], 1);
            dst[pos] = (int)(((unsigned)my[k].y & 0xFFFF0000u) | ((unsigned)my[k].x & 0xFFFFu));
        }
    }
    __syncthreads();

    // gather: wave w owns nodes dl = w*16..w*16+15. Oct split: 8 lane-groups
    // of 8; group g processes payload 8*o+g, each lane loads uint4 (16 B =
    // 8 batches). ONE VMEM instr per EIGHT payloads. 3-level shfl_xor
    // combine across groups; lanes 0-7 store dwordx4.
    const uint4* __restrict__ xq = (const uint4*)xth;   // [N][8] uint4 rows
    int lane = tid & 63;
    int g  = lane >> 3;                 // payload slot within oct (0..7)
    int bl = lane & 7;                  // 16B chunk: batches 8*bl..8*bl+7
    int wid = tid >> 6;
    for (int t = 0; t < BKT_NODES / 8; ++t) {
        int dl = wid * (BKT_NODES / 8) + t;
        int v = v0 + dl;
        if (v >= N) continue;                       // wave-uniform
        const int* pay = dst + pb[dl] + g;          // this group's payload lane
        int noct = ((cnt[dl] + 7) & ~7) >> 3;
        float a0 = 0.f, a1 = 0.f, a2 = 0.f, a3 = 0.f;
        float a4 = 0.f, a5 = 0.f, a6 = 0.f, a7 = 0.f;
        int o = 0;
        for (; o + 4 <= noct; o += 4) {
            int pA = pay[8 * o];
            int pB = pay[8 * o + 8];
            int pC = pay[8 * o + 16];
            int pD = pay[8 * o + 24];
            uint4 dA = xq[(((size_t)((unsigned)pA & 0xFFFFu)) << 3) + bl];
            uint4 dB = xq[(((size_t)((unsigned)pB & 0xFFFFu)) << 3) + bl];
            uint4 dC = xq[(((size_t)((unsigned)pC & 0xFFFFu)) << 3) + bl];
            uint4 dD = xq[(((size_t)((unsigned)pD & 0xFFFFu)) << 3) + bl];
            ACC8(pA, dA)
            ACC8(pB, dB)
            ACC8(pC, dC)
            ACC8(pD, dD)
        }
        for (; o < noct; ++o) {
            int p = pay[8 * o];
            uint4 d = xq[(((size_t)((unsigned)p & 0xFFFFu)) << 3) + bl];
            ACC8(p, d)
        }
        // combine the 8 payload-group partial sums (xor over lane bits 3,4,5
        // keeps batch index lane&7 invariant)
        COMB3(a0) COMB3(a1) COMB3(a2) COMB3(a3)
        COMB3(a4) COMB3(a5) COMB3(a6) COMB3(a7)
        if (lane < 8) {
            __half2 h0 = __floats2half2_rn(a0, a1);
            __half2 h1 = __floats2half2_rn(a2, a3);
            __half2 h2 = __floats2half2_rn(a4, a5);
            __half2 h3 = __floats2half2_rn(a6, a7);
            uint4 st = make_uint4(*(unsigned*)&h0, *(unsigned*)&h1,
                                  *(unsigned*)&h2, *(unsigned*)&h3);
            *(uint4*)(msg + ((size_t)side * N + v) * 64 + 8 * lane) = st;
        }
    }
}

// kernel 4: epilogue from original x [64,N]; LDS-transpose fp16 msg tiles.
__global__ void final_kernel(const float* __restrict__ x,
                             const __half* __restrict__ msg,
                             const float* __restrict__ colsum,
                             const float* __restrict__ br, const float* __restrict__ bd,
                             float* __restrict__ out, int N) {
    __shared__ float tr[64][65];
    __shared__ float td[64][65];
    int v0 = blockIdx.x * 64;
    int tx = threadIdx.x;
    int ty = threadIdx.y;
    for (int vl = ty; vl < 64; vl += 16) {
        int v = v0 + vl;
        if (v < N) {
            tr[vl][tx] = __half2float(msg[(size_t)v * 64 + tx]);               // msgr
            td[vl][tx] = __half2float(msg[((size_t)N + v) * 64 + tx]);         // msgd
        }
    }
    __syncthreads();
    int v = v0 + tx;
    if (v < N) {
        float cold = colsum[v];              // side 0: sum wd over e: ei=v
        float colr = colsum[(size_t)N + v];  // side 1: sum wr over e: ej=v
        float brv = br[v], bdv = bd[v];
        for (int b = ty; b < 64; b += 16) {
            float xv = x[b * N + v];
            float r = colr * xv - tr[tx][b] + brv;
            float d = cold * xv - td[tx][b] + bdv;
            out[b * N + v] = tanhf(r) + d + xv;
        }
    }
}

extern "C" void kernel_launch(void* const* d_in, const int* in_sizes, int n_in,
                              void* d_out, int out_size, void* d_ws, size_t ws_size,
                              hipStream_t stream) {
    const float* x  = (const float*)d_in[1];
    const int*   ei = (const int*)d_in[2];
    const int*   ej = (const int*)d_in[3];
    const float* wr = (const float*)d_in[4];
    const float* wd = (const float*)d_in[5];
    const float* br = (const float*)d_in[6];
    const float* bd = (const float*)d_in[7];
    float* out = (float*)d_out;

    int E = in_sizes[2];
    int N = in_sizes[6];
    int NB = (N + BKT_NODES - 1) >> BKT_SHIFT;
    (void)out_size; (void)ws_size; (void)n_in;

    // workspace: xth[N*64 f16] | msg[2*N*64 f16] | colsum[2N f32]
    //          | cnt_node[2N int] | gcur[2NB] | runs[2*NB*RCAP int2]  (~48 MB)
    // colsum/cnt_node/gcur contiguous -> zeroed together by transpose.
    char* w = (char*)d_ws;
    __half* xth = (__half*)w;    w += (size_t)N * 64 * 2;
    __half* msg = (__half*)w;    w += (size_t)2 * N * 64 * 2;
    float* colsum = (float*)w;   w += (size_t)2 * N * 4;
    int* cnt_node = (int*)w;     w += (size_t)2 * N * 4;
    int* gcur   = (int*)w;       w += (size_t)2 * NB * 4;
    w = (char*)(((uintptr_t)w + 15) & ~(uintptr_t)15);
    int2* runs  = (int2*)w;

    int nz = 4 * N + 2 * NB;     // ints to zero, starting at colsum

    dim3 tb(64, 16);
    int ntiles = (N + 63) / 64;
    transpose_kernel<<<ntiles, tb, 0, stream>>>(x, xth, (int*)colsum, nz, N);

    int nchunks = (E + CH - 1) / CH;
    partition_kernel<<<nchunks, 512, 0, stream>>>(ei, ej, wr, wd, gcur, runs,
                                                  cnt_node, colsum, E, NB, N);

    sortgather_kernel<<<2 * NB, 512, 0, stream>>>(gcur, runs, cnt_node, xth,
                                                  msg, NB, N);

    final_kernel<<<ntiles, tb, 0, stream>>>(x, msg, colsum, br, bd, out, N);
}

// Round 5
// 206.056 us; speedup vs baseline: 2.1834x; 2.1834x over previous
//
#include <hip/hip_runtime.h>
#include <hip/hip_fp16.h>

// reaction_diffusion, 4-kernel pipeline (R16: fixed-capacity LDS placement --
// pass A + scan eliminated; R15's global atomics reverted):
//   1. transpose: x[64,N] -> xth[N,64] fp16 (+ zero gcur)
//   2. partition: dual-side bucket multisplit (512 thr, 76KB LDS, 2 blocks/CU,
//      391 chunks: ONE round)  [exact R12 form]
//   3. sortgather: one 512-thr block per (side,bucket). Each node owns a FIXED
//      CAP=80 slot segment in LDS (Poisson(32): P(deg>=80)~1e-11). Zero dst
//      (b128), then ONE pass over payloads: pos=rtnAtomic(cur[dl]),
//      dst[dl*80+pos]=w_main|other, f32Atomic(csum[dl], w_col). 3 LDS
//      ops/payload (was 4: R14/R15 ledger shows pass A+B LDS ops = 45 of 80us;
//      gather = 34us at ~12 TB/s L2-random, insensitive to instrs/hit-level).
//      No count load, no scan, no pad loop, 2 barriers (was 5). Gather:
//      oct-split uint4 (1 VMEM per 8 payloads), 3-level shfl_xor combine,
//      lanes 0-7 store uint4; lane 0 writes colsum.
//   4. final: out[b,v] = tanh(colr*x - msgr + br) + (cold*x - msgd + bd) + x
// side 0 (dest = ei): w_main=wr -> msgr, w_col=wd -> cold
// side 1 (dest = ej): w_main=wd -> msgd, w_col=wr -> colr
// stage-1 payload int2: x=(bkt:9<<23)|(dl:7<<16)|(other:16), y=bf16(wm)<<16|bf16(wc)
// sorted payload int: (bf16(wm)<<16)|other:16   -- requires N <= 65536
// NEVER per-edge global atomics (R15: 25.6M atomics = +230us, 9ns each).

#define BKT_SHIFT 7
#define BKT_NODES 128
#define RCAP 4608     // per-(side,bucket) run capacity: mean 4096, +8 sigma
#define CAP 80        // per-node fixed slot capacity (deg tail ~1e-11)
#define CH 4096       // partition chunk size (= 8 * 512 threads)
#define NBP 512       // padded per-side bin count (N <= 65536)

__device__ __forceinline__ unsigned bf16_rne(float f) {
    unsigned u = __float_as_uint(f);
    unsigned rb = (u >> 16) & 1u;
    u += 0x7FFFu + rb;
    return u >> 16;
}
__device__ __forceinline__ float bf16_lo(int y) {
    return __uint_as_float(((unsigned)y) << 16);
}
__device__ __forceinline__ float bf16_hi(int y) {
    return __uint_as_float((unsigned)y & 0xFFFF0000u);
}

// kernel 1: x [64,N] -> xth [N,64] fp16; also zeroes gcur.
__global__ void transpose_kernel(const float* __restrict__ x, __half* __restrict__ xth,
                                 int* __restrict__ gcur, int ngcur, int N) {
    __shared__ float tile[64][65];
    int v0 = blockIdx.x * 64;
    int tx = threadIdx.x;   // 0..63
    int ty = threadIdx.y;   // 0..15
    int flat = blockIdx.x * 1024 + ty * 64 + tx;
    if (flat < ngcur) gcur[flat] = 0;
    if (v0 + tx < N) {
        for (int b = ty; b < 64; b += 16)
            tile[tx][b] = x[b * N + v0 + tx];
    }
    __syncthreads();
    for (int vl = ty; vl < 64; vl += 16) {
        int v = v0 + vl;
        if (v < N)
            xth[(size_t)v * 64 + tx] = __float2half(tile[vl][tx]);
    }
}

// kernel 2: dual-side chunked multi-split; edges in registers (read once).
__global__ void __launch_bounds__(512) partition_kernel(
        const int* __restrict__ ei, const int* __restrict__ ej,
        const float* __restrict__ wr, const float* __restrict__ wd,
        int* __restrict__ gcur, int2* __restrict__ runs,
        int E, int NB) {
    __shared__ int cnt[2 * NBP];     // 4 KB
    __shared__ int base_a[2 * NBP];  // 4 KB
    __shared__ int gb[2 * NBP];      // 4 KB
    __shared__ int2 buf[2 * CH];     // 64 KB

    int tid = threadIdx.x;
    int e0 = blockIdx.x * CH;
    int ch_len = min(CH, E - e0);
    if (ch_len <= 0) return;

    int my_i[8], my_j[8];
    unsigned my_w[8];
    #pragma unroll
    for (int k = 0; k < 8; ++k) {
        int t = tid + k * 512;
        if (t < ch_len) {
            int e = e0 + t;
            my_i[k] = ei[e];
            my_j[k] = ej[e];
            my_w[k] = (bf16_rne(wr[e]) << 16) | bf16_rne(wd[e]);
        } else {
            my_i[k] = -1;
        }
    }

    for (int b = tid; b < 2 * NBP; b += 512) cnt[b] = 0;
    __syncthreads();
    #pragma unroll
    for (int k = 0; k < 8; ++k) {
        if (my_i[k] >= 0) {
            atomicAdd(&cnt[my_i[k] >> BKT_SHIFT], 1);
            atomicAdd(&cnt[NBP + (my_j[k] >> BKT_SHIFT)], 1);
        }
    }
    __syncthreads();
    if (tid < 64) {
        int carry = 0;
        #pragma unroll
        for (int c = 0; c < (2 * NBP) / 64; ++c) {
            int idx = c * 64 + tid;
            int val = cnt[idx];
            int scan = val;
            for (int off = 1; off < 64; off <<= 1) {
                int n = __shfl_up(scan, off, 64);
                if (tid >= off) scan += n;
            }
            int excl = scan - val + carry;
            base_a[idx] = excl;
            cnt[idx] = excl;            // becomes cursor
            carry += __shfl(scan, 63, 64);
        }
    }
    __syncthreads();
    #pragma unroll
    for (int k = 0; k < 8; ++k) {
        if (my_i[k] >= 0) {
            int i = my_i[k], j = my_j[k];
            unsigned wv = my_w[k];
            int b0 = i >> BKT_SHIFT;
            int p0 = atomicAdd(&cnt[b0], 1);
            buf[p0] = make_int2((int)(((unsigned)b0 << 23) | ((unsigned)(i & 127) << 16) | (unsigned)j),
                                (int)wv);
            int b1 = j >> BKT_SHIFT;
            int p1 = atomicAdd(&cnt[NBP + b1], 1);
            buf[p1] = make_int2((int)(((unsigned)b1 << 23) | ((unsigned)(j & 127) << 16) | (unsigned)i),
                                (int)((wv << 16) | (wv >> 16)));
        }
    }
    __syncthreads();
    for (int cb = tid; cb < 2 * NBP; cb += 512) {
        int n = cnt[cb] - base_a[cb];
        if (n > 0) {
            int side = cb >> 9;
            int bkt = cb & (NBP - 1);
            gb[cb] = atomicAdd(&gcur[side * NB + bkt], n);
        }
    }
    __syncthreads();
    int total = 2 * ch_len;
    for (int t = tid; t < total; t += 512) {
        int2 p = buf[t];
        int side = (t >= ch_len) ? 1 : 0;
        int bkt = ((unsigned)p.x >> 23) & 0x1FF;
        int cb = side * NBP + bkt;
        int rank = gb[cb] + (t - base_a[cb]);
        if (rank < RCAP)
            runs[((size_t)(side * NB + bkt)) * RCAP + rank] = p;
    }
}

// accumulate one payload (weight in hi16 of P, 8 batches from uint4 D)
#define ACC8(P, D)                                                        \
    {                                                                     \
        float wv_ = bf16_hi(P);                                           \
        float2 f_;                                                        \
        f_ = __half22float2(*(const __half2*)&(D).x);                     \
        a0 = fmaf(wv_, f_.x, a0); a1 = fmaf(wv_, f_.y, a1);               \
        f_ = __half22float2(*(const __half2*)&(D).y);                     \
        a2 = fmaf(wv_, f_.x, a2); a3 = fmaf(wv_, f_.y, a3);               \
        f_ = __half22float2(*(const __half2*)&(D).z);                     \
        a4 = fmaf(wv_, f_.x, a4); a5 = fmaf(wv_, f_.y, a5);               \
        f_ = __half22float2(*(const __half2*)&(D).w);                     \
        a6 = fmaf(wv_, f_.x, a6); a7 = fmaf(wv_, f_.y, a7);               \
    }

#define COMB3(A) { A += __shfl_xor(A, 8); A += __shfl_xor(A, 16); A += __shfl_xor(A, 32); }

// kernel 3: per (side,bucket): stage runs into 9 int2 regs (single nt read),
// zero fixed-cap dst, ONE placement pass (rtn atomic + write + f32 csum
// atomic), then oct-split uint4 gather. ~42 KB LDS, 512 thr, 3 blk/CU
// (grid-limited).
__global__ void __launch_bounds__(512) sortgather_kernel(
        const int* __restrict__ gcur, const int2* __restrict__ runs,
        const __half* __restrict__ xth,
        __half* __restrict__ msg, float* __restrict__ colsum,
        int NB, int N) {
    __shared__ int cur[BKT_NODES];
    __shared__ float csum[BKT_NODES];
    __shared__ int dst[BKT_NODES * CAP];        // 40 KB, node dl owns [dl*CAP, dl*CAP+CAP)

    int sb = blockIdx.x;               // side*NB + b
    int side = (sb >= NB) ? 1 : 0;
    int b = sb - side * NB;
    int v0 = b << BKT_SHIFT;
    int len = min(gcur[sb], RCAP);
    size_t roff = (size_t)sb * RCAP;
    int tid = threadIdx.x;

    // register-stage the whole run: 9 * 512 = 4608 = RCAP. Single global read,
    // nontemporal (keep xth rows hotter in L2). Valid payloads never have
    // x == -1 (bkt field <= 390 < 511).
    int2 my[9];
    #pragma unroll
    for (int k = 0; k < 9; ++k) {
        int t = tid + k * 512;
        if (t < len) {
            long long raw = __builtin_nontemporal_load((const long long*)(runs + roff + t));
            my[k].x = (int)(unsigned)(raw & 0xFFFFFFFFll);
            my[k].y = (int)(unsigned)((unsigned long long)raw >> 32);
        } else my[k].x = -1;
    }

    // zero cur/csum and the whole dst array (pads read as w=0, other=0)
    if (tid < BKT_NODES) { cur[tid] = 0; csum[tid] = 0.f; }
    {
        int4* d4 = (int4*)dst;
        #pragma unroll
        for (int k = 0; k < (BKT_NODES * CAP) / (4 * 512); ++k)
            d4[tid + k * 512] = make_int4(0, 0, 0, 0);
    }
    __syncthreads();
    // placement: 1 rtn LDS atomic + 1 ds_write + 1 f32 LDS atomic per payload
    #pragma unroll
    for (int k = 0; k < 9; ++k) {
        if (my[k].x != -1) {
            int dl = ((unsigned)my[k].x >> 16) & 0x7F;
            int pos = atomicAdd(&cur[dl], 1);
            if (pos < CAP)
                dst[dl * CAP + pos] =
                    (int)(((unsigned)my[k].y & 0xFFFF0000u) | ((unsigned)my[k].x & 0xFFFFu));
            atomicAdd(&csum[dl], bf16_lo(my[k].y));
        }
    }
    __syncthreads();

    // gather: wave w owns nodes dl = w*16..w*16+15. Oct split: 8 lane-groups
    // of 8; group g processes payload 8*o+g, each lane loads uint4 (16 B =
    // 8 batches). ONE VMEM instr per EIGHT payloads. 3-level shfl_xor
    // combine across groups; lanes 0-7 store dwordx4.
    const uint4* __restrict__ xq = (const uint4*)xth;   // [N][8] uint4 rows
    int lane = tid & 63;
    int g  = lane >> 3;                 // payload slot within oct (0..7)
    int bl = lane & 7;                  // 16B chunk: batches 8*bl..8*bl+7
    int wid = tid >> 6;
    for (int t = 0; t < BKT_NODES / 8; ++t) {
        int dl = wid * (BKT_NODES / 8) + t;
        int v = v0 + dl;
        if (v >= N) continue;                       // wave-uniform
        const int* pay = dst + dl * CAP + g;        // this group's payload lane
        int cnt = min(cur[dl], CAP);
        int noct = (cnt + 7) >> 3;                  // <= CAP/8 = 10
        float a0 = 0.f, a1 = 0.f, a2 = 0.f, a3 = 0.f;
        float a4 = 0.f, a5 = 0.f, a6 = 0.f, a7 = 0.f;
        int o = 0;
        for (; o + 4 <= noct; o += 4) {
            int pA = pay[8 * o];
            int pB = pay[8 * o + 8];
            int pC = pay[8 * o + 16];
            int pD = pay[8 * o + 24];
            uint4 dA = xq[(((size_t)((unsigned)pA & 0xFFFFu)) << 3) + bl];
            uint4 dB = xq[(((size_t)((unsigned)pB & 0xFFFFu)) << 3) + bl];
            uint4 dC = xq[(((size_t)((unsigned)pC & 0xFFFFu)) << 3) + bl];
            uint4 dD = xq[(((size_t)((unsigned)pD & 0xFFFFu)) << 3) + bl];
            ACC8(pA, dA)
            ACC8(pB, dB)
            ACC8(pC, dC)
            ACC8(pD, dD)
        }
        for (; o < noct; ++o) {
            int p = pay[8 * o];
            uint4 d = xq[(((size_t)((unsigned)p & 0xFFFFu)) << 3) + bl];
            ACC8(p, d)
        }
        // combine the 8 payload-group partial sums (xor over lane bits 3,4,5
        // keeps batch index lane&7 invariant)
        COMB3(a0) COMB3(a1) COMB3(a2) COMB3(a3)
        COMB3(a4) COMB3(a5) COMB3(a6) COMB3(a7)
        if (lane < 8) {
            __half2 h0 = __floats2half2_rn(a0, a1);
            __half2 h1 = __floats2half2_rn(a2, a3);
            __half2 h2 = __floats2half2_rn(a4, a5);
            __half2 h3 = __floats2half2_rn(a6, a7);
            uint4 st = make_uint4(*(unsigned*)&h0, *(unsigned*)&h1,
                                  *(unsigned*)&h2, *(unsigned*)&h3);
            *(uint4*)(msg + ((size_t)side * N + v) * 64 + 8 * lane) = st;
        }
        if (lane == 0)
            colsum[(size_t)side * N + v] = csum[dl];
    }
}

// kernel 4: epilogue from original x [64,N]; LDS-transpose fp16 msg tiles.
__global__ void final_kernel(const float* __restrict__ x,
                             const __half* __restrict__ msg,
                             const float* __restrict__ colsum,
                             const float* __restrict__ br, const float* __restrict__ bd,
                             float* __restrict__ out, int N) {
    __shared__ float tr[64][65];
    __shared__ float td[64][65];
    int v0 = blockIdx.x * 64;
    int tx = threadIdx.x;
    int ty = threadIdx.y;
    for (int vl = ty; vl < 64; vl += 16) {
        int v = v0 + vl;
        if (v < N) {
            tr[vl][tx] = __half2float(msg[(size_t)v * 64 + tx]);               // msgr
            td[vl][tx] = __half2float(msg[((size_t)N + v) * 64 + tx]);         // msgd
        }
    }
    __syncthreads();
    int v = v0 + tx;
    if (v < N) {
        float cold = colsum[v];              // side 0: sum wd over e: ei=v
        float colr = colsum[(size_t)N + v];  // side 1: sum wr over e: ej=v
        float brv = br[v], bdv = bd[v];
        for (int b = ty; b < 64; b += 16) {
            float xv = x[b * N + v];
            float r = colr * xv - tr[tx][b] + brv;
            float d = cold * xv - td[tx][b] + bdv;
            out[b * N + v] = tanhf(r) + d + xv;
        }
    }
}

extern "C" void kernel_launch(void* const* d_in, const int* in_sizes, int n_in,
                              void* d_out, int out_size, void* d_ws, size_t ws_size,
                              hipStream_t stream) {
    const float* x  = (const float*)d_in[1];
    const int*   ei = (const int*)d_in[2];
    const int*   ej = (const int*)d_in[3];
    const float* wr = (const float*)d_in[4];
    const float* wd = (const float*)d_in[5];
    const float* br = (const float*)d_in[6];
    const float* bd = (const float*)d_in[7];
    float* out = (float*)d_out;

    int E = in_sizes[2];
    int N = in_sizes[6];
    int NB = (N + BKT_NODES - 1) >> BKT_SHIFT;
    (void)out_size; (void)ws_size; (void)n_in;

    // workspace: xth[N*64 f16] | msg[2*N*64 f16] | colsum[2N f32] | gcur[2NB]
    //          | runs[2*NB*RCAP int2]   (~48 MB)
    char* w = (char*)d_ws;
    __half* xth = (__half*)w;    w += (size_t)N * 64 * 2;
    __half* msg = (__half*)w;    w += (size_t)2 * N * 64 * 2;
    float* colsum = (float*)w;   w += (size_t)2 * N * 4;
    int* gcur   = (int*)w;       w += (size_t)2 * NB * 4;
    w = (char*)(((uintptr_t)w + 15) & ~(uintptr_t)15);
    int2* runs  = (int2*)w;

    dim3 tb(64, 16);
    int ntiles = (N + 63) / 64;
    transpose_kernel<<<ntiles, tb, 0, stream>>>(x, xth, gcur, 2 * NB, N);

    int nchunks = (E + CH - 1) / CH;
    partition_kernel<<<nchunks, 512, 0, stream>>>(ei, ej, wr, wd, gcur, runs, E, NB);

    sortgather_kernel<<<2 * NB, 512, 0, stream>>>(gcur, runs, xth, msg, colsum, NB, N);

    final_kernel<<<ntiles, tb, 0, stream>>>(x, msg, colsum, br, bd, out, N);
}

// Round 6
// 194.280 us; speedup vs baseline: 2.3157x; 1.0606x over previous
//
#include <hip/hip_runtime.h>
#include <hip/hip_fp16.h>

// reaction_diffusion, 4-kernel pipeline (R17: half-bucket split sortgather —
// 2 blocks per (side,bucket), 64 nodes each, to double wave occupancy):
//   1. transpose: x[64,N] -> xth[N,64] fp16 (+ zero gcur)
//   2. partition: dual-side bucket multisplit (512 thr, 76KB LDS, 2 blocks/CU,
//      391 chunks: ONE round)  [R12 form, unchanged]
//   3. sortgather: TWO 512-thr blocks per (side,bucket); block h owns nodes
//      [64h,64h+64). Stages the full run (9 int2 nt regs), places only owned
//      payloads (predicated) into fixed-cap dst[64*80] (20.7 KB LDS ->
//      wave-slot-capped 4 blk/CU = 32 waves = 100% occupancy; R16 post-mortem:
//      78us invariant to LDS-op count/instr count/hit level, VALU 73% idle,
//      occupancy 40% at 3 blk/CU -> latency-bound on wave slots). Gather:
//      oct-split uint4 (1 VMEM per 8 payloads), 3-level shfl_xor combine,
//      lanes 0-7 store uint4; lane 0 writes colsum.
//   4. final: out[b,v] = tanh(colr*x - msgr + br) + (cold*x - msgd + bd) + x
// side 0 (dest = ei): w_main=wr -> msgr, w_col=wd -> cold
// side 1 (dest = ej): w_main=wd -> msgd, w_col=wr -> colr
// stage-1 payload int2: x=(bkt:9<<23)|(dl:7<<16)|(other:16), y=bf16(wm)<<16|bf16(wc)
// placed payload int: (bf16(wm)<<16)|other:16   -- requires N <= 65536
// NEVER per-edge global atomics (R15: 25.6M atomics = +230us, 9ns each).

#define BKT_SHIFT 7
#define BKT_NODES 128
#define HALF_NODES 64
#define RCAP 4608     // per-(side,bucket) run capacity: mean 4096, +8 sigma
#define CAP 80        // per-node fixed slot capacity (deg tail ~1e-11)
#define CH 4096       // partition chunk size (= 8 * 512 threads)
#define NBP 512       // padded per-side bin count (N <= 65536)

__device__ __forceinline__ unsigned bf16_rne(float f) {
    unsigned u = __float_as_uint(f);
    unsigned rb = (u >> 16) & 1u;
    u += 0x7FFFu + rb;
    return u >> 16;
}
__device__ __forceinline__ float bf16_lo(int y) {
    return __uint_as_float(((unsigned)y) << 16);
}
__device__ __forceinline__ float bf16_hi(int y) {
    return __uint_as_float((unsigned)y & 0xFFFF0000u);
}

// kernel 1: x [64,N] -> xth [N,64] fp16; also zeroes gcur.
__global__ void transpose_kernel(const float* __restrict__ x, __half* __restrict__ xth,
                                 int* __restrict__ gcur, int ngcur, int N) {
    __shared__ float tile[64][65];
    int v0 = blockIdx.x * 64;
    int tx = threadIdx.x;   // 0..63
    int ty = threadIdx.y;   // 0..15
    int flat = blockIdx.x * 1024 + ty * 64 + tx;
    if (flat < ngcur) gcur[flat] = 0;
    if (v0 + tx < N) {
        for (int b = ty; b < 64; b += 16)
            tile[tx][b] = x[b * N + v0 + tx];
    }
    __syncthreads();
    for (int vl = ty; vl < 64; vl += 16) {
        int v = v0 + vl;
        if (v < N)
            xth[(size_t)v * 64 + tx] = __float2half(tile[vl][tx]);
    }
}

// kernel 2: dual-side chunked multi-split; edges in registers (read once).
__global__ void __launch_bounds__(512) partition_kernel(
        const int* __restrict__ ei, const int* __restrict__ ej,
        const float* __restrict__ wr, const float* __restrict__ wd,
        int* __restrict__ gcur, int2* __restrict__ runs,
        int E, int NB) {
    __shared__ int cnt[2 * NBP];     // 4 KB
    __shared__ int base_a[2 * NBP];  // 4 KB
    __shared__ int gb[2 * NBP];      // 4 KB
    __shared__ int2 buf[2 * CH];     // 64 KB

    int tid = threadIdx.x;
    int e0 = blockIdx.x * CH;
    int ch_len = min(CH, E - e0);
    if (ch_len <= 0) return;

    int my_i[8], my_j[8];
    unsigned my_w[8];
    #pragma unroll
    for (int k = 0; k < 8; ++k) {
        int t = tid + k * 512;
        if (t < ch_len) {
            int e = e0 + t;
            my_i[k] = ei[e];
            my_j[k] = ej[e];
            my_w[k] = (bf16_rne(wr[e]) << 16) | bf16_rne(wd[e]);
        } else {
            my_i[k] = -1;
        }
    }

    for (int b = tid; b < 2 * NBP; b += 512) cnt[b] = 0;
    __syncthreads();
    #pragma unroll
    for (int k = 0; k < 8; ++k) {
        if (my_i[k] >= 0) {
            atomicAdd(&cnt[my_i[k] >> BKT_SHIFT], 1);
            atomicAdd(&cnt[NBP + (my_j[k] >> BKT_SHIFT)], 1);
        }
    }
    __syncthreads();
    if (tid < 64) {
        int carry = 0;
        #pragma unroll
        for (int c = 0; c < (2 * NBP) / 64; ++c) {
            int idx = c * 64 + tid;
            int val = cnt[idx];
            int scan = val;
            for (int off = 1; off < 64; off <<= 1) {
                int n = __shfl_up(scan, off, 64);
                if (tid >= off) scan += n;
            }
            int excl = scan - val + carry;
            base_a[idx] = excl;
            cnt[idx] = excl;            // becomes cursor
            carry += __shfl(scan, 63, 64);
        }
    }
    __syncthreads();
    #pragma unroll
    for (int k = 0; k < 8; ++k) {
        if (my_i[k] >= 0) {
            int i = my_i[k], j = my_j[k];
            unsigned wv = my_w[k];
            int b0 = i >> BKT_SHIFT;
            int p0 = atomicAdd(&cnt[b0], 1);
            buf[p0] = make_int2((int)(((unsigned)b0 << 23) | ((unsigned)(i & 127) << 16) | (unsigned)j),
                                (int)wv);
            int b1 = j >> BKT_SHIFT;
            int p1 = atomicAdd(&cnt[NBP + b1], 1);
            buf[p1] = make_int2((int)(((unsigned)b1 << 23) | ((unsigned)(j & 127) << 16) | (unsigned)i),
                                (int)((wv << 16) | (wv >> 16)));
        }
    }
    __syncthreads();
    for (int cb = tid; cb < 2 * NBP; cb += 512) {
        int n = cnt[cb] - base_a[cb];
        if (n > 0) {
            int side = cb >> 9;
            int bkt = cb & (NBP - 1);
            gb[cb] = atomicAdd(&gcur[side * NB + bkt], n);
        }
    }
    __syncthreads();
    int total = 2 * ch_len;
    for (int t = tid; t < total; t += 512) {
        int2 p = buf[t];
        int side = (t >= ch_len) ? 1 : 0;
        int bkt = ((unsigned)p.x >> 23) & 0x1FF;
        int cb = side * NBP + bkt;
        int rank = gb[cb] + (t - base_a[cb]);
        if (rank < RCAP)
            runs[((size_t)(side * NB + bkt)) * RCAP + rank] = p;
    }
}

// accumulate one payload (weight in hi16 of P, 8 batches from uint4 D)
#define ACC8(P, D)                                                        \
    {                                                                     \
        float wv_ = bf16_hi(P);                                           \
        float2 f_;                                                        \
        f_ = __half22float2(*(const __half2*)&(D).x);                     \
        a0 = fmaf(wv_, f_.x, a0); a1 = fmaf(wv_, f_.y, a1);               \
        f_ = __half22float2(*(const __half2*)&(D).y);                     \
        a2 = fmaf(wv_, f_.x, a2); a3 = fmaf(wv_, f_.y, a3);               \
        f_ = __half22float2(*(const __half2*)&(D).z);                     \
        a4 = fmaf(wv_, f_.x, a4); a5 = fmaf(wv_, f_.y, a5);               \
        f_ = __half22float2(*(const __half2*)&(D).w);                     \
        a6 = fmaf(wv_, f_.x, a6); a7 = fmaf(wv_, f_.y, a7);               \
    }

#define COMB3(A) { A += __shfl_xor(A, 8); A += __shfl_xor(A, 16); A += __shfl_xor(A, 32); }

// kernel 3: 2 blocks per (side,bucket); block h owns nodes [64h, 64h+64).
// Stage full run into 9 int2 regs (nt), zero 64-node fixed-cap dst, ONE
// predicated placement pass, oct-split uint4 gather. ~21 KB LDS, 512 thr,
// 4 blk/CU (wave-slot cap) = 100% occupancy.
__global__ void __launch_bounds__(512) sortgather_kernel(
        const int* __restrict__ gcur, const int2* __restrict__ runs,
        const __half* __restrict__ xth,
        __half* __restrict__ msg, float* __restrict__ colsum,
        int NB, int N) {
    __shared__ int cur[HALF_NODES];
    __shared__ float csum[HALF_NODES];
    __shared__ int dst[HALF_NODES * CAP];   // 20 KB, node dll owns [dll*CAP, +CAP)

    int blk = blockIdx.x;
    int sb = blk >> 1;                 // side*NB + b
    int h  = blk & 1;                  // bucket half
    int side = (sb >= NB) ? 1 : 0;
    int b = sb - side * NB;
    int v0 = (b << BKT_SHIFT) + h * HALF_NODES;
    int len = min(gcur[sb], RCAP);
    size_t roff = (size_t)sb * RCAP;
    int tid = threadIdx.x;

    // register-stage the whole run: 9 * 512 = 4608 = RCAP. Single global read,
    // nontemporal. Valid payloads never have x == -1 (bkt field <= 390 < 511).
    int2 my[9];
    #pragma unroll
    for (int k = 0; k < 9; ++k) {
        int t = tid + k * 512;
        if (t < len) {
            long long raw = __builtin_nontemporal_load((const long long*)(runs + roff + t));
            my[k].x = (int)(unsigned)(raw & 0xFFFFFFFFll);
            my[k].y = (int)(unsigned)((unsigned long long)raw >> 32);
        } else my[k].x = -1;
    }

    // zero cur/csum and the whole dst array (pads read as w=0, other=0)
    if (tid < HALF_NODES) { cur[tid] = 0; csum[tid] = 0.f; }
    {
        int4* d4 = (int4*)dst;
        for (int idx = tid; idx < (HALF_NODES * CAP) / 4; idx += 512)
            d4[idx] = make_int4(0, 0, 0, 0);
    }
    __syncthreads();
    // placement: predicated on ownership (dl's half == h).
    #pragma unroll
    for (int k = 0; k < 9; ++k) {
        if (my[k].x != -1) {
            int dl = ((unsigned)my[k].x >> 16) & 0x7F;
            if ((dl >> 6) == h) {
                int dll = dl & (HALF_NODES - 1);
                int pos = atomicAdd(&cur[dll], 1);
                if (pos < CAP)
                    dst[dll * CAP + pos] =
                        (int)(((unsigned)my[k].y & 0xFFFF0000u) | ((unsigned)my[k].x & 0xFFFFu));
                atomicAdd(&csum[dll], bf16_lo(my[k].y));
            }
        }
    }
    __syncthreads();

    // gather: wave w owns nodes dll = w*8..w*8+7. Oct split: 8 lane-groups
    // of 8; group g processes payload 8*o+g, each lane loads uint4 (16 B =
    // 8 batches). ONE VMEM instr per EIGHT payloads. 3-level shfl_xor
    // combine across groups; lanes 0-7 store dwordx4.
    const uint4* __restrict__ xq = (const uint4*)xth;   // [N][8] uint4 rows
    int lane = tid & 63;
    int g  = lane >> 3;                 // payload slot within oct (0..7)
    int bl = lane & 7;                  // 16B chunk: batches 8*bl..8*bl+7
    int wid = tid >> 6;
    for (int t = 0; t < HALF_NODES / 8; ++t) {
        int dll = wid * (HALF_NODES / 8) + t;
        int v = v0 + dll;
        if (v >= N) continue;                       // wave-uniform
        const int* pay = dst + dll * CAP + g;       // this group's payload lane
        int cnt = min(cur[dll], CAP);
        int noct = (cnt + 7) >> 3;                  // <= CAP/8 = 10
        float a0 = 0.f, a1 = 0.f, a2 = 0.f, a3 = 0.f;
        float a4 = 0.f, a5 = 0.f, a6 = 0.f, a7 = 0.f;
        int o = 0;
        for (; o + 4 <= noct; o += 4) {
            int pA = pay[8 * o];
            int pB = pay[8 * o + 8];
            int pC = pay[8 * o + 16];
            int pD = pay[8 * o + 24];
            uint4 dA = xq[(((size_t)((unsigned)pA & 0xFFFFu)) << 3) + bl];
            uint4 dB = xq[(((size_t)((unsigned)pB & 0xFFFFu)) << 3) + bl];
            uint4 dC = xq[(((size_t)((unsigned)pC & 0xFFFFu)) << 3) + bl];
            uint4 dD = xq[(((size_t)((unsigned)pD & 0xFFFFu)) << 3) + bl];
            ACC8(pA, dA)
            ACC8(pB, dB)
            ACC8(pC, dC)
            ACC8(pD, dD)
        }
        for (; o < noct; ++o) {
            int p = pay[8 * o];
            uint4 d = xq[(((size_t)((unsigned)p & 0xFFFFu)) << 3) + bl];
            ACC8(p, d)
        }
        // combine the 8 payload-group partial sums (xor over lane bits 3,4,5
        // keeps batch index lane&7 invariant)
        COMB3(a0) COMB3(a1) COMB3(a2) COMB3(a3)
        COMB3(a4) COMB3(a5) COMB3(a6) COMB3(a7)
        if (lane < 8) {
            __half2 h0 = __floats2half2_rn(a0, a1);
            __half2 h1 = __floats2half2_rn(a2, a3);
            __half2 h2 = __floats2half2_rn(a4, a5);
            __half2 h3 = __floats2half2_rn(a6, a7);
            uint4 st = make_uint4(*(unsigned*)&h0, *(unsigned*)&h1,
                                  *(unsigned*)&h2, *(unsigned*)&h3);
            *(uint4*)(msg + ((size_t)side * N + v) * 64 + 8 * lane) = st;
        }
        if (lane == 0)
            colsum[(size_t)side * N + v] = csum[dll];
    }
}

// kernel 4: epilogue from original x [64,N]; LDS-transpose fp16 msg tiles.
__global__ void final_kernel(const float* __restrict__ x,
                             const __half* __restrict__ msg,
                             const float* __restrict__ colsum,
                             const float* __restrict__ br, const float* __restrict__ bd,
                             float* __restrict__ out, int N) {
    __shared__ float tr[64][65];
    __shared__ float td[64][65];
    int v0 = blockIdx.x * 64;
    int tx = threadIdx.x;
    int ty = threadIdx.y;
    for (int vl = ty; vl < 64; vl += 16) {
        int v = v0 + vl;
        if (v < N) {
            tr[vl][tx] = __half2float(msg[(size_t)v * 64 + tx]);               // msgr
            td[vl][tx] = __half2float(msg[((size_t)N + v) * 64 + tx]);         // msgd
        }
    }
    __syncthreads();
    int v = v0 + tx;
    if (v < N) {
        float cold = colsum[v];              // side 0: sum wd over e: ei=v
        float colr = colsum[(size_t)N + v];  // side 1: sum wr over e: ej=v
        float brv = br[v], bdv = bd[v];
        for (int b = ty; b < 64; b += 16) {
            float xv = x[b * N + v];
            float r = colr * xv - tr[tx][b] + brv;
            float d = cold * xv - td[tx][b] + bdv;
            out[b * N + v] = tanhf(r) + d + xv;
        }
    }
}

extern "C" void kernel_launch(void* const* d_in, const int* in_sizes, int n_in,
                              void* d_out, int out_size, void* d_ws, size_t ws_size,
                              hipStream_t stream) {
    const float* x  = (const float*)d_in[1];
    const int*   ei = (const int*)d_in[2];
    const int*   ej = (const int*)d_in[3];
    const float* wr = (const float*)d_in[4];
    const float* wd = (const float*)d_in[5];
    const float* br = (const float*)d_in[6];
    const float* bd = (const float*)d_in[7];
    float* out = (float*)d_out;

    int E = in_sizes[2];
    int N = in_sizes[6];
    int NB = (N + BKT_NODES - 1) >> BKT_SHIFT;
    (void)out_size; (void)ws_size; (void)n_in;

    // workspace: xth[N*64 f16] | msg[2*N*64 f16] | colsum[2N f32] | gcur[2NB]
    //          | runs[2*NB*RCAP int2]   (~48 MB)
    char* w = (char*)d_ws;
    __half* xth = (__half*)w;    w += (size_t)N * 64 * 2;
    __half* msg = (__half*)w;    w += (size_t)2 * N * 64 * 2;
    float* colsum = (float*)w;   w += (size_t)2 * N * 4;
    int* gcur   = (int*)w;       w += (size_t)2 * NB * 4;
    w = (char*)(((uintptr_t)w + 15) & ~(uintptr_t)15);
    int2* runs  = (int2*)w;

    dim3 tb(64, 16);
    int ntiles = (N + 63) / 64;
    transpose_kernel<<<ntiles, tb, 0, stream>>>(x, xth, gcur, 2 * NB, N);

    int nchunks = (E + CH - 1) / CH;
    partition_kernel<<<nchunks, 512, 0, stream>>>(ei, ej, wr, wd, gcur, runs, E, NB);

    sortgather_kernel<<<4 * NB, 512, 0, stream>>>(gcur, runs, xth, msg, colsum, NB, N);

    final_kernel<<<ntiles, tb, 0, stream>>>(x, msg, colsum, br, bd, out, N);
}